// Round 9
// baseline (100.336 us; speedup 1.0000x reference)
//
#include <hip/hip_runtime.h>
#include <hip/hip_bf16.h>

#define CIN  64
#define HH   128
#define WW   128
#define COUT 128
#define HO   126
#define WO   126
#define NB   32
#define HW   (HH * WW)

typedef __bf16 bf16x8 __attribute__((ext_vector_type(8)));
typedef float f32x4  __attribute__((ext_vector_type(4)));
typedef float f32x16 __attribute__((ext_vector_type(16)));

// ws granule layout: [s(9)][g8(8)][cout(128)] 16B granules
// granule(s,g8,cout)[j] = bf16(w[cout][ci = 8*g8 + j][s])
__global__ void wreorder_3556(const float* __restrict__ w, unsigned short* __restrict__ ws2) {
    int e = blockIdx.x * 256 + threadIdx.x;      // 0..73727
    if (e >= 73728) return;
    int j = e & 7, cout = (e >> 3) & 127, g8 = (e >> 10) & 7, s = e >> 13;
    __bf16 v = (__bf16)w[cout * 576 + (g8 * 8 + j) * 9 + s];
    ws2[e] = __builtin_bit_cast(unsigned short, v);
}

// LDS: xs [row(4)][cg(8)][col(128)] 16B granules @0 = 64KB | pmin[2][2][128] f32 @65536
// B-reads may overflow xs by <=32B into pmin region: garbage -> discarded out cols 126/127.
#define XS_OFF  0
#define PM_OFF  65536
#define SMEM_BYTES (65536 + 4096)   // 69632 -> 2 blocks/CU

template<bool USE_WS>
__global__ __launch_bounds__(512, 4)
void conv_min_tanh_3556(const float* __restrict__ x, const float* __restrict__ w,
                        const float* __restrict__ bias,
                        const unsigned char* __restrict__ wsr_b,
                        float* __restrict__ out) {
    __shared__ __align__(16) unsigned char smem[SMEM_BYTES];
    float* pmin = (float*)(smem + PM_OFF);

    // XCD-chunked bijective swizzle (2016 = 8 * 252)
    const int bid = blockIdx.x;
    const int blk = (bid & 7) * 252 + (bid >> 3);
    const int b   = blk / 63;
    const int R   = (blk - b * 63) * 2;       // base output row; covers ho = R, R+1

    const int tid  = threadIdx.x;
    const int lane = tid & 63;
    const int wid  = tid >> 6;                // 0..7
    const int l31 = lane & 31;
    const int l5  = lane >> 5;
    const int waveM  = wid & 1;               // cout half
    const int waveN  = (wid >> 1) & 1;        // col half
    const int waveHO = wid >> 2;              // ho within pair
    const int mb = waveM * 64;
    const int cb = waveN * 64;

    // ---- stage x rows R..R+3 into xs[row][cg][col] granules (f32x4 loads + in-reg transpose)
    {
        #pragma unroll
        for (int it = 0; it < 2; ++it) {
            int item = it * 512 + tid;            // 0..1023
            int col4 = item & 31;
            int cig  = (item >> 5) & 7;
            int row  = item >> 8;                 // 0..3
            const float* src = x + (size_t)b * CIN * HW + (size_t)(cig * 8) * HW
                                 + (size_t)(R + row) * WW + col4 * 4;
            f32x4 v[8];
            #pragma unroll
            for (int j = 0; j < 8; ++j) v[j] = *(const f32x4*)(src + (size_t)j * HW);
            #pragma unroll
            for (int c = 0; c < 4; ++c) {
                union { unsigned short us[8]; int4 i4; } p;
                #pragma unroll
                for (int j = 0; j < 8; ++j) {
                    __bf16 t = (__bf16)v[j][c];
                    p.us[j] = __builtin_bit_cast(unsigned short, t);
                }
                *(int4*)(smem + XS_OFF + (((row * 8 + cig) * 128) + col4 * 4 + c) * 16) = p.i4;
            }
        }
    }
    __syncthreads();

    // ---- B read bases: addr = (waveHO+kh)*16384 + ks*4096 + baseB[n][kw]
    int baseB[2][3];
    #pragma unroll
    for (int n = 0; n < 2; ++n)
        #pragma unroll
        for (int kw = 0; kw < 3; ++kw)
            baseB[n][kw] = XS_OFF + (cb + n * 32 + l31 + kw) * 16 + l5 * 2048;

    // ---- A base: offset(s,ks,m) = s*16384 + ks*4096 + m*512 (+ per-thread base)
    const unsigned char* wA = USE_WS ? (wsr_b + l5 * 2048 + (size_t)(mb + l31) * 16) : nullptr;

    f32x16 acc[2][2] = {};   // [m][n]

    #pragma unroll
    for (int s = 0; s < 9; ++s) {
        const int kh = s / 3, kw = s % 3;          // compile-time after unroll
        const int rowOff = (waveHO + kh) * 16384;

        #pragma unroll
        for (int ks = 0; ks < 4; ++ks) {
            bf16x8 A0, A1, B0, B1;
            if constexpr (USE_WS) {
                A0 = *(const bf16x8*)(wA + s * 16384 + ks * 4096);
                A1 = *(const bf16x8*)(wA + s * 16384 + ks * 4096 + 512);
            } else {
                #pragma unroll
                for (int j = 0; j < 8; ++j) {
                    A0[j] = (__bf16)w[(mb + l31) * 576 + ((ks * 2 + l5) * 8 + j) * 9 + s];
                    A1[j] = (__bf16)w[(mb + 32 + l31) * 576 + ((ks * 2 + l5) * 8 + j) * 9 + s];
                }
            }
            B0 = *(const bf16x8*)(smem + rowOff + ks * 4096 + baseB[0][kw]);
            B1 = *(const bf16x8*)(smem + rowOff + ks * 4096 + baseB[1][kw]);

            acc[0][0] = __builtin_amdgcn_mfma_f32_32x32x16_bf16(A0, B0, acc[0][0], 0, 0, 0);
            acc[0][1] = __builtin_amdgcn_mfma_f32_32x32x16_bf16(A0, B1, acc[0][1], 0, 0, 0);
            acc[1][0] = __builtin_amdgcn_mfma_f32_32x32x16_bf16(A1, B0, acc[1][0], 0, 0, 0);
            acc[1][1] = __builtin_amdgcn_mfma_f32_32x32x16_bf16(A1, B1, acc[1][1], 0, 0, 0);
        }
    }

    // ---- epilogue: +bias, min over 128 couts (2 m-tiles + 16 regs + lane32 swap)
    float pm[2] = {1e30f, 1e30f};
    #pragma unroll
    for (int m = 0; m < 2; ++m) {
        #pragma unroll
        for (int r = 0; r < 16; ++r) {
            float bv = bias[mb + m * 32 + (r & 3) + 8 * (r >> 2) + 4 * l5];
            pm[0] = fminf(pm[0], acc[m][0][r] + bv);
            pm[1] = fminf(pm[1], acc[m][1][r] + bv);
        }
    }
    pm[0] = fminf(pm[0], __shfl_xor(pm[0], 32, 64));
    pm[1] = fminf(pm[1], __shfl_xor(pm[1], 32, 64));
    if (l5 == 0) {
        pmin[(waveM * 2 + waveHO) * 128 + cb + l31]      = pm[0];
        pmin[(waveM * 2 + waveHO) * 128 + cb + 32 + l31] = pm[1];
    }
    __syncthreads();

    if (tid < 2 * WO) {
        int hh  = tid / WO;
        int col = tid - hh * WO;
        float v = fminf(pmin[(0 * 2 + hh) * 128 + col], pmin[(1 * 2 + hh) * 128 + col]);
        v = tanhf(tanhf(v));
        out[((size_t)b * HO + R + hh) * WO + col] = v;
    }
}

extern "C" void kernel_launch(void* const* d_in, const int* in_sizes, int n_in,
                              void* d_out, int out_size, void* d_ws, size_t ws_size,
                              hipStream_t stream) {
    const float* x    = (const float*)d_in[0];
    const float* w    = (const float*)d_in[1];
    const float* bias = (const float*)d_in[2];
    float* out = (float*)d_out;

    const size_t ws_needed = (size_t)9 * 8 * 128 * 16;   // 147456 B
    if (ws_size >= ws_needed) {
        unsigned short* wsb = (unsigned short*)d_ws;
        wreorder_3556<<<288, 256, 0, stream>>>(w, wsb);
        conv_min_tanh_3556<true><<<NB * (HO / 2), 512, 0, stream>>>(x, w, bias, (const unsigned char*)wsb, out);
    } else {
        conv_min_tanh_3556<false><<<NB * (HO / 2), 512, 0, stream>>>(x, w, bias, nullptr, out);
    }
}

// Round 10
// 91.976 us; speedup vs baseline: 1.0909x; 1.0909x over previous
//
#include <hip/hip_runtime.h>
#include <hip/hip_bf16.h>

#define CIN  64
#define HH   128
#define WW   128
#define COUT 128
#define HO   126
#define WO   126
#define NB   32
#define HW   (HH * WW)

typedef __bf16 bf16x8 __attribute__((ext_vector_type(8)));
typedef float f32x16 __attribute__((ext_vector_type(16)));

#define SGB(mask, n) __builtin_amdgcn_sched_group_barrier((mask), (n), 0)

// ws2 granule layout: [step(18)=(s,h)][kg(4)][cout(128)] 16B granules
// granule(step,kg,cout)[j] = bf16(w[cout][ci = 32h + 8kg + j][s])
__global__ void wreorder_3556(const float* __restrict__ w, unsigned short* __restrict__ ws2) {
    int e = blockIdx.x * 256 + threadIdx.x;      // 0..73727
    if (e >= 73728) return;
    int j = e & 7, cout = (e >> 3) & 127, kg = (e >> 10) & 3, h = (e >> 12) & 1, s = e >> 13;
    __bf16 v = (__bf16)w[cout * 576 + (h * 32 + kg * 8 + j) * 9 + s];
    ws2[e] = __builtin_bit_cast(unsigned short, v);
}

// LDS: xs [row(3)][cg(8)][col(130)] 16B granules (ci-major) @0 | pmin[2][128] @49920
#define XS_OFF  0
#define PM_OFF  49920
#define SMEM_BYTES (49920 + 2 * 128 * 4)   // 50944 -> 3 blocks/CU

template<bool USE_WS>
__global__ __launch_bounds__(256, 3)
void conv_min_tanh_3556(const float* __restrict__ x, const float* __restrict__ w,
                        const float* __restrict__ bias,
                        const unsigned char* __restrict__ wsr_b,
                        float* __restrict__ out) {
    __shared__ __align__(16) unsigned char smem[SMEM_BYTES];
    float* pmin = (float*)(smem + PM_OFF);

    // XCD-chunked bijective swizzle (4032 % 8 == 0)
    const int bid = blockIdx.x;
    const int blk = (bid & 7) * (NB * HO / 8) + (bid >> 3);
    const int b  = blk / HO;
    const int ho = blk - b * HO;

    const int tid  = threadIdx.x;
    const int lane = tid & 63;
    const int wid  = tid >> 6;
    const int l31 = lane & 31;
    const int l5  = lane >> 5;
    const int mb  = (wid >> 1) * 64;     // cout base (0 or 64)
    const int cb  = (wid & 1) * 64;      // col base  (0 or 64)

    // ---- stage x into xs[row][cg][col] granules; conflict-free 16B-stride writes
    {
        const int cg = tid >> 5, c0 = tid & 31;
        const float* xb = x + (size_t)b * CIN * HW + (size_t)(cg * 8) * HW + (size_t)ho * WW + c0;
        #pragma unroll
        for (int row = 0; row < 3; ++row) {
            #pragma unroll
            for (int i = 0; i < 4; ++i) {
                union { unsigned short us[8]; int4 i4; } p;
                #pragma unroll
                for (int j = 0; j < 8; ++j) {
                    __bf16 t = (__bf16)xb[(size_t)j * HW + (size_t)row * WW + i * 32];
                    p.us[j] = __builtin_bit_cast(unsigned short, t);
                }
                *(int4*)(smem + XS_OFF + ((row * 8 + cg) * 130 + i * 32 + c0) * 16) = p.i4;
            }
        }
        if (tid < 48) {   // zero-pad cols 128,129
            int row = tid >> 4, cgz = (tid >> 1) & 7, colz = 128 + (tid & 1);
            int4 z = {0, 0, 0, 0};
            *(int4*)(smem + XS_OFF + ((row * 8 + cgz) * 130 + colz) * 16) = z;
        }
    }
    __syncthreads();

    // ---- B read bases (stride-16B across lanes: conflict-free)
    // full addr = (kh*8 + h*4 + ks*2)*2080 + baseB[n][kw]
    int baseB[2][3];
    #pragma unroll
    for (int n = 0; n < 2; ++n)
        #pragma unroll
        for (int kw = 0; kw < 3; ++kw)
            baseB[n][kw] = XS_OFF + (cb + n * 32 + l31 + kw) * 16 + l5 * 2080;

    // ---- A stream base: granule(step, kg=2ks+l5, cout=mb+m*32+l31)
    const unsigned char* wA = USE_WS ? (wsr_b + l5 * 2048 + (size_t)(mb + l31) * 16) : nullptr;

    auto LOAD_A = [&](int step, int ks, int m) -> bf16x8 {
        if constexpr (USE_WS) {
            return *(const bf16x8*)(wA + (size_t)step * 8192 + ks * 4096 + m * 512);
        } else {
            int s = step >> 1, h = step & 1;
            bf16x8 r;
            #pragma unroll
            for (int j = 0; j < 8; ++j)
                r[j] = (__bf16)w[(mb + m * 32 + l31) * 576 +
                                 (h * 32 + (2 * ks + l5) * 8 + j) * 9 + s];
            return r;
        }
    };
    auto LOAD_B = [&](int step, int ks, int n) -> bf16x8 {
        const int s = step >> 1, h = step & 1;
        const int kh = s / 3, kw = s % 3;
        return *(const bf16x8*)(smem + (kh * 8 + h * 4 + ks * 2) * 2080 + baseB[n][kw]);
    };

    // ---- 2-slot register pipeline: slot(step&1) holds step's fragments
    bf16x8 A2[2][2][2], B2[2][2][2];    // [slot][ks][m|n]
    #pragma unroll
    for (int ks = 0; ks < 2; ++ks)
        #pragma unroll
        for (int q = 0; q < 2; ++q) {
            A2[0][ks][q] = LOAD_A(0, ks, q);
            B2[0][ks][q] = LOAD_B(0, ks, q);
        }

    f32x16 acc[2][2] = {};

    #pragma unroll
    for (int step = 0; step < 18; ++step) {
        const int cur = step & 1, nxt = cur ^ 1;

        // issue step+1 loads FIRST (SGB pins them before this step's MFMAs)
        if (step + 1 < 18) {
            #pragma unroll
            for (int ks = 0; ks < 2; ++ks) {
                B2[nxt][ks][0] = LOAD_B(step + 1, ks, 0);
                B2[nxt][ks][1] = LOAD_B(step + 1, ks, 1);
                A2[nxt][ks][0] = LOAD_A(step + 1, ks, 0);
                A2[nxt][ks][1] = LOAD_A(step + 1, ks, 1);
            }
        }

        #pragma unroll
        for (int ks = 0; ks < 2; ++ks)
            #pragma unroll
            for (int m = 0; m < 2; ++m)
                #pragma unroll
                for (int n = 0; n < 2; ++n)
                    acc[m][n] = __builtin_amdgcn_mfma_f32_32x32x16_bf16(
                        A2[cur][ks][m], B2[cur][ks][n], acc[m][n], 0, 0, 0);

        // compile-time schedule pin: {4 DS_READ}{4 VMEM_READ}{8 MFMA} per step
        SGB(0x100, 4);   // DS_READ  : B(step+1)
        SGB(0x020, 4);   // VMEM_READ: A(step+1)
        SGB(0x008, 8);   // MFMA     : step
    }

    // ---- epilogue: +bias, min over couts, cross-lane, cross-wave, tanh(tanh)
    float pm[2] = {1e30f, 1e30f};
    #pragma unroll
    for (int m = 0; m < 2; ++m) {
        #pragma unroll
        for (int r = 0; r < 16; ++r) {
            int row = mb + m * 32 + (r & 3) + 8 * (r >> 2) + 4 * l5;
            float bv = bias[row];
            pm[0] = fminf(pm[0], acc[m][0][r] + bv);
            pm[1] = fminf(pm[1], acc[m][1][r] + bv);
        }
    }
    pm[0] = fminf(pm[0], __shfl_xor(pm[0], 32, 64));
    pm[1] = fminf(pm[1], __shfl_xor(pm[1], 32, 64));
    if (l5 == 0) {
        pmin[(wid >> 1) * 128 + cb + l31]      = pm[0];
        pmin[(wid >> 1) * 128 + cb + 32 + l31] = pm[1];
    }
    __syncthreads();
    if (tid < WO) {
        float v = fminf(pmin[tid], pmin[128 + tid]);
        v = tanhf(tanhf(v));
        out[((size_t)b * HO + ho) * WO + tid] = v;
    }
}

extern "C" void kernel_launch(void* const* d_in, const int* in_sizes, int n_in,
                              void* d_out, int out_size, void* d_ws, size_t ws_size,
                              hipStream_t stream) {
    const float* x    = (const float*)d_in[0];
    const float* w    = (const float*)d_in[1];
    const float* bias = (const float*)d_in[2];
    float* out = (float*)d_out;

    const size_t ws_needed = (size_t)18 * 4 * 128 * 16;   // 147456 B
    if (ws_size >= ws_needed) {
        unsigned short* wsb = (unsigned short*)d_ws;
        wreorder_3556<<<288, 256, 0, stream>>>(w, wsb);
        conv_min_tanh_3556<true><<<NB * HO, 256, 0, stream>>>(x, w, bias, (const unsigned char*)wsb, out);
    } else {
        conv_min_tanh_3556<false><<<NB * HO, 256, 0, stream>>>(x, w, bias, nullptr, out);
    }
}

// Round 11
// 88.243 us; speedup vs baseline: 1.1370x; 1.0423x over previous
//
#include <hip/hip_runtime.h>
#include <hip/hip_bf16.h>

#define CIN  64
#define HH   128
#define WW   128
#define COUT 128
#define HO   126
#define WO   126
#define NB   32
#define HW   (HH * WW)

typedef __bf16 bf16x8 __attribute__((ext_vector_type(8)));
typedef float f32x16 __attribute__((ext_vector_type(16)));

// ws2 granule layout: [step(18)=(s,h)][kg(4)][cout(128)] 16B granules
// granule(step,kg,cout)[j] = bf16(w[cout][ci = 32h + 8kg + j][s])
__global__ void wreorder_3556(const float* __restrict__ w, unsigned short* __restrict__ ws2) {
    int e = blockIdx.x * 256 + threadIdx.x;      // 0..73727
    if (e >= 73728) return;
    int j = e & 7, cout = (e >> 3) & 127, kg = (e >> 10) & 3, h = (e >> 12) & 1, s = e >> 13;
    __bf16 v = (__bf16)w[cout * 576 + (h * 32 + kg * 8 + j) * 9 + s];
    ws2[e] = __builtin_bit_cast(unsigned short, v);
}

// LDS: xs [row(3)][cg(8)][col(130)] 16B granules (ci-major) @0 | pmin[2][128] @49920
#define XS_OFF  0
#define PM_OFF  49920
#define SMEM_BYTES (49920 + 2 * 128 * 4)   // 50944

__device__ __forceinline__ unsigned lds_addr(const void* p) {
    return (unsigned)(unsigned long long)(const __attribute__((address_space(3))) unsigned char*)p;
}

template<int OFF>
__device__ __forceinline__ bf16x8 ds_read128(unsigned base) {
    bf16x8 d;
    asm volatile("ds_read_b128 %0, %1 offset:%c2" : "=v"(d) : "v"(base), "i"(OFF));
    return d;
}
template<int OFF>
__device__ __forceinline__ bf16x8 glob_load128(const unsigned char* sbase, unsigned voff) {
    bf16x8 d;
    asm volatile("global_load_dwordx4 %0, %1, %2 offset:%c3"
                 : "=v"(d) : "v"(voff), "s"(sbase), "i"(OFF));
    return d;
}

// step T: s = T>>1 (slice), h = T&1 (ci half); kh = s/3, kw = s%3
#define KWOF(T) (((T) >> 1) % 3)
#define OFFB(T, KS) (((((T) >> 1) / 3) * 8 + ((T) & 1) * 4 + (KS) * 2) * 2080)

template<bool USE_WS>
__global__ __launch_bounds__(256, 2)
void conv_min_tanh_3556(const float* __restrict__ x, const float* __restrict__ w,
                        const float* __restrict__ bias,
                        const unsigned char* __restrict__ wsr_b,
                        float* __restrict__ out) {
    __shared__ __align__(16) unsigned char smem[SMEM_BYTES];
    float* pmin = (float*)(smem + PM_OFF);

    // XCD-chunked bijective swizzle (4032 % 8 == 0)
    const int bid = blockIdx.x;
    const int blk = (bid & 7) * (NB * HO / 8) + (bid >> 3);
    const int b  = blk / HO;
    const int ho = blk - b * HO;

    const int tid  = threadIdx.x;
    const int lane = tid & 63;
    const int wid  = tid >> 6;
    const int l31 = lane & 31;
    const int l5  = lane >> 5;
    const int mb  = (wid >> 1) * 64;     // cout base (0 or 64)
    const int cb  = (wid & 1) * 64;      // col base  (0 or 64)

    // ---- stage x into xs[row][cg][col] granules; conflict-free 16B-stride writes
    {
        const int cg = tid >> 5, c0 = tid & 31;
        const float* xb = x + (size_t)b * CIN * HW + (size_t)(cg * 8) * HW + (size_t)ho * WW + c0;
        #pragma unroll
        for (int row = 0; row < 3; ++row) {
            #pragma unroll
            for (int i = 0; i < 4; ++i) {
                union { unsigned short us[8]; int4 i4; } p;
                #pragma unroll
                for (int j = 0; j < 8; ++j) {
                    __bf16 t = (__bf16)xb[(size_t)j * HW + (size_t)row * WW + i * 32];
                    p.us[j] = __builtin_bit_cast(unsigned short, t);
                }
                *(int4*)(smem + XS_OFF + ((row * 8 + cg) * 130 + i * 32 + c0) * 16) = p.i4;
            }
        }
        if (tid < 48) {   // zero-pad cols 128,129
            int row = tid >> 4, cgz = (tid >> 1) & 7, colz = 128 + (tid & 1);
            int4 z = {0, 0, 0, 0};
            *(int4*)(smem + XS_OFF + ((row * 8 + cgz) * 130 + colz) * 16) = z;
        }
    }
    __syncthreads();

    f32x16 acc[2][2] = {};

    if constexpr (USE_WS) {
        // ---- B base LDS addresses (conflict-free: stride-16B across lanes)
        unsigned bB[2][3];
        #pragma unroll
        for (int n = 0; n < 2; ++n)
            #pragma unroll
            for (int kw = 0; kw < 3; ++kw)
                bB[n][kw] = lds_addr(smem) + (unsigned)((cb + n * 32 + l31 + kw) * 16 + l5 * 2080);

        // ---- A voffset base: granule(step, kg = 2ks+l5, cout = mb+m*32+l31)
        const unsigned voffA = (unsigned)(l5 * 2048 + (mb + l31) * 16);

        bf16x8 A4[4][2][2], B4[4][2][2];   // [slot][ks][m|n]

        #define PRELOAD(T) do {                                                   \
            B4[T][0][0] = ds_read128<OFFB(T,0)>(bB[0][KWOF(T)]);                  \
            B4[T][0][1] = ds_read128<OFFB(T,0)>(bB[1][KWOF(T)]);                  \
            B4[T][1][0] = ds_read128<OFFB(T,1)>(bB[0][KWOF(T)]);                  \
            B4[T][1][1] = ds_read128<OFFB(T,1)>(bB[1][KWOF(T)]);                  \
            A4[T][0][0] = glob_load128<0>(wsr_b,   voffA + (T) * 8192);           \
            A4[T][0][1] = glob_load128<512>(wsr_b, voffA + (T) * 8192);           \
            A4[T][1][0] = glob_load128<0>(wsr_b,   voffA + (T) * 8192 + 4096);    \
            A4[T][1][1] = glob_load128<512>(wsr_b, voffA + (T) * 8192 + 4096);    \
        } while (0)

        PRELOAD(0); PRELOAD(1); PRELOAD(2);

        #define KSTEP(T) do {                                                     \
            if ((T) <= 15)      asm volatile("s_waitcnt lgkmcnt(8) vmcnt(8)" ::: "memory"); \
            else if ((T) == 16) asm volatile("s_waitcnt lgkmcnt(4) vmcnt(4)" ::: "memory"); \
            else                asm volatile("s_waitcnt lgkmcnt(0) vmcnt(0)" ::: "memory"); \
            __builtin_amdgcn_sched_barrier(0);                                    \
            {   const int sl = (T) & 3;                                           \
                acc[0][0] = __builtin_amdgcn_mfma_f32_32x32x16_bf16(A4[sl][0][0], B4[sl][0][0], acc[0][0], 0, 0, 0); \
                acc[0][1] = __builtin_amdgcn_mfma_f32_32x32x16_bf16(A4[sl][0][0], B4[sl][0][1], acc[0][1], 0, 0, 0); \
                acc[1][0] = __builtin_amdgcn_mfma_f32_32x32x16_bf16(A4[sl][0][1], B4[sl][0][0], acc[1][0], 0, 0, 0); \
                acc[1][1] = __builtin_amdgcn_mfma_f32_32x32x16_bf16(A4[sl][0][1], B4[sl][0][1], acc[1][1], 0, 0, 0); \
                acc[0][0] = __builtin_amdgcn_mfma_f32_32x32x16_bf16(A4[sl][1][0], B4[sl][1][0], acc[0][0], 0, 0, 0); \
                acc[0][1] = __builtin_amdgcn_mfma_f32_32x32x16_bf16(A4[sl][1][0], B4[sl][1][1], acc[0][1], 0, 0, 0); \
                acc[1][0] = __builtin_amdgcn_mfma_f32_32x32x16_bf16(A4[sl][1][1], B4[sl][1][0], acc[1][0], 0, 0, 0); \
                acc[1][1] = __builtin_amdgcn_mfma_f32_32x32x16_bf16(A4[sl][1][1], B4[sl][1][1], acc[1][1], 0, 0, 0); \
            }                                                                     \
            __builtin_amdgcn_sched_barrier(0);                                    \
            if ((T) + 3 <= 17) { PRELOAD_SLOT((T) + 3); }                         \
        } while (0)

        #define PRELOAD_SLOT(T) do { const int ns = (T) & 3;                      \
            B4[ns][0][0] = ds_read128<OFFB(T,0)>(bB[0][KWOF(T)]);                 \
            B4[ns][0][1] = ds_read128<OFFB(T,0)>(bB[1][KWOF(T)]);                 \
            B4[ns][1][0] = ds_read128<OFFB(T,1)>(bB[0][KWOF(T)]);                 \
            B4[ns][1][1] = ds_read128<OFFB(T,1)>(bB[1][KWOF(T)]);                 \
            A4[ns][0][0] = glob_load128<0>(wsr_b,   voffA + (T) * 8192);          \
            A4[ns][0][1] = glob_load128<512>(wsr_b, voffA + (T) * 8192);          \
            A4[ns][1][0] = glob_load128<0>(wsr_b,   voffA + (T) * 8192 + 4096);   \
            A4[ns][1][1] = glob_load128<512>(wsr_b, voffA + (T) * 8192 + 4096);   \
        } while (0)

        KSTEP(0);  KSTEP(1);  KSTEP(2);  KSTEP(3);  KSTEP(4);  KSTEP(5);
        KSTEP(6);  KSTEP(7);  KSTEP(8);  KSTEP(9);  KSTEP(10); KSTEP(11);
        KSTEP(12); KSTEP(13); KSTEP(14); KSTEP(15); KSTEP(16); KSTEP(17);

        asm volatile("s_waitcnt lgkmcnt(0) vmcnt(0)" ::: "memory");
        __builtin_amdgcn_sched_barrier(0);
    } else {
        // fallback: simple non-pipelined loop straight from w
        int baseB[2][3];
        #pragma unroll
        for (int n = 0; n < 2; ++n)
            #pragma unroll
            for (int kw = 0; kw < 3; ++kw)
                baseB[n][kw] = XS_OFF + (cb + n * 32 + l31 + kw) * 16 + l5 * 2080;
        #pragma unroll
        for (int step = 0; step < 18; ++step) {
            const int s = step >> 1, h = step & 1;
            const int kh = s / 3, kw = s % 3;
            #pragma unroll
            for (int ks = 0; ks < 2; ++ks) {
                bf16x8 a0, a1, b0, b1;
                #pragma unroll
                for (int j = 0; j < 8; ++j) {
                    a0[j] = (__bf16)w[(mb + l31) * 576 + (h * 32 + (2 * ks + l5) * 8 + j) * 9 + s];
                    a1[j] = (__bf16)w[(mb + 32 + l31) * 576 + (h * 32 + (2 * ks + l5) * 8 + j) * 9 + s];
                }
                b0 = *(const bf16x8*)(smem + (kh * 8 + h * 4 + ks * 2) * 2080 + baseB[0][kw]);
                b1 = *(const bf16x8*)(smem + (kh * 8 + h * 4 + ks * 2) * 2080 + baseB[1][kw]);
                acc[0][0] = __builtin_amdgcn_mfma_f32_32x32x16_bf16(a0, b0, acc[0][0], 0, 0, 0);
                acc[0][1] = __builtin_amdgcn_mfma_f32_32x32x16_bf16(a0, b1, acc[0][1], 0, 0, 0);
                acc[1][0] = __builtin_amdgcn_mfma_f32_32x32x16_bf16(a1, b0, acc[1][0], 0, 0, 0);
                acc[1][1] = __builtin_amdgcn_mfma_f32_32x32x16_bf16(a1, b1, acc[1][1], 0, 0, 0);
            }
        }
    }

    // ---- epilogue: +bias, min over couts, cross-lane, cross-wave, tanh(tanh)
    float pm[2] = {1e30f, 1e30f};
    #pragma unroll
    for (int m = 0; m < 2; ++m) {
        #pragma unroll
        for (int r = 0; r < 16; ++r) {
            int row = mb + m * 32 + (r & 3) + 8 * (r >> 2) + 4 * l5;
            float bv = bias[row];
            pm[0] = fminf(pm[0], acc[m][0][r] + bv);
            pm[1] = fminf(pm[1], acc[m][1][r] + bv);
        }
    }
    pm[0] = fminf(pm[0], __shfl_xor(pm[0], 32, 64));
    pm[1] = fminf(pm[1], __shfl_xor(pm[1], 32, 64));
    if (l5 == 0) {
        pmin[(wid >> 1) * 128 + cb + l31]      = pm[0];
        pmin[(wid >> 1) * 128 + cb + 32 + l31] = pm[1];
    }
    __syncthreads();
    if (tid < WO) {
        float v = fminf(pmin[tid], pmin[128 + tid]);
        v = tanhf(tanhf(v));
        out[((size_t)b * HO + ho) * WO + tid] = v;
    }
}

extern "C" void kernel_launch(void* const* d_in, const int* in_sizes, int n_in,
                              void* d_out, int out_size, void* d_ws, size_t ws_size,
                              hipStream_t stream) {
    const float* x    = (const float*)d_in[0];
    const float* w    = (const float*)d_in[1];
    const float* bias = (const float*)d_in[2];
    float* out = (float*)d_out;

    const size_t ws_needed = (size_t)18 * 4 * 128 * 16;   // 147456 B
    if (ws_size >= ws_needed) {
        unsigned short* wsb = (unsigned short*)d_ws;
        wreorder_3556<<<288, 256, 0, stream>>>(w, wsb);
        conv_min_tanh_3556<true><<<NB * HO, 256, 0, stream>>>(x, w, bias, (const unsigned char*)wsb, out);
    } else {
        conv_min_tanh_3556<false><<<NB * HO, 256, 0, stream>>>(x, w, bias, nullptr, out);
    }
}

// Round 12
// 81.285 us; speedup vs baseline: 1.2344x; 1.0856x over previous
//
#include <hip/hip_runtime.h>
#include <hip/hip_bf16.h>

#define CIN  64
#define HH   128
#define WW   128
#define COUT 128
#define HO   126
#define WO   126
#define NB   32
#define HW   (HH * WW)

typedef __bf16 bf16x8 __attribute__((ext_vector_type(8)));
typedef float f32x16 __attribute__((ext_vector_type(16)));

// ws2 granule layout: [step(18)=(s,h)][kg(4)][cout(128)] 16B granules
// granule(step,kg,cout)[j] = bf16(w[cout][ci = 32h + 8kg + j][s])
__global__ void wreorder_3556(const float* __restrict__ w, unsigned short* __restrict__ ws2) {
    int e = blockIdx.x * 256 + threadIdx.x;      // 0..73727
    if (e >= 73728) return;
    int j = e & 7, cout = (e >> 3) & 127, kg = (e >> 10) & 3, h = (e >> 12) & 1, s = e >> 13;
    __bf16 v = (__bf16)w[cout * 576 + (h * 32 + kg * 8 + j) * 9 + s];
    ws2[e] = __builtin_bit_cast(unsigned short, v);
}

// LDS: xs [row(4)][cg(8)][col(130)] 16B granules (ci-major) @0 = 66560 | pmin[4][128] @66560
#define XS_OFF  0
#define PM_OFF  66560
#define SMEM_BYTES (66560 + 4 * 128 * 4)   // 68608 -> 2 blocks/CU

template<bool USE_WS>
__global__ __launch_bounds__(256, 2)
void conv_min_tanh_3556(const float* __restrict__ x, const float* __restrict__ w,
                        const float* __restrict__ bias,
                        const unsigned char* __restrict__ wsr_b,
                        float* __restrict__ out) {
    __shared__ __align__(16) unsigned char smem[SMEM_BYTES];
    float* pmin = (float*)(smem + PM_OFF);

    // XCD-chunked bijective swizzle (2016 = 8 * 252)
    const int bid = blockIdx.x;
    const int blk = (bid & 7) * 252 + (bid >> 3);
    const int b   = blk / 63;
    const int R   = (blk - b * 63) * 2;      // output rows R, R+1; input rows R..R+3

    const int tid  = threadIdx.x;
    const int lane = tid & 63;
    const int wid  = tid >> 6;               // 0..3
    const int l31 = lane & 31;
    const int l5  = lane >> 5;
    const int waveM = wid & 1;               // cout half
    const int waveR = wid >> 1;              // output row within pair
    const int mb = waveM * 64;

    // ---- stage x rows R..R+3 into xs[row][cg][col] granules (R6 conflict-free pattern)
    {
        const int cg = tid >> 5, c0 = tid & 31;
        const float* xb = x + (size_t)b * CIN * HW + (size_t)(cg * 8) * HW + (size_t)R * WW + c0;
        #pragma unroll
        for (int row = 0; row < 4; ++row) {
            #pragma unroll
            for (int i = 0; i < 4; ++i) {
                union { unsigned short us[8]; int4 i4; } p;
                #pragma unroll
                for (int j = 0; j < 8; ++j) {
                    __bf16 t = (__bf16)xb[(size_t)j * HW + (size_t)row * WW + i * 32];
                    p.us[j] = __builtin_bit_cast(unsigned short, t);
                }
                *(int4*)(smem + XS_OFF + ((row * 8 + cg) * 130 + i * 32 + c0) * 16) = p.i4;
            }
        }
        if (tid < 64) {   // zero-pad cols 128,129 for all 4 rows
            int row = tid >> 4, cgz = (tid >> 1) & 7, colz = 128 + (tid & 1);
            int4 z = {0, 0, 0, 0};
            *(int4*)(smem + XS_OFF + ((row * 8 + cgz) * 130 + colz) * 16) = z;
        }
    }
    __syncthreads();

    // ---- A stream base: granule(step, kg = 2ks+l5, cout = mb + m*32 + l31)
    const unsigned char* wA = USE_WS ? (wsr_b + l5 * 2048 + (size_t)(mb + l31) * 16) : nullptr;

    f32x16 acc[2][4] = {};   // [m][n] : 64 cout x 128 col

    #pragma unroll
    for (int step = 0; step < 18; ++step) {
        const int s = step >> 1, h = step & 1;
        const int kh = s / 3, kw = s % 3;          // compile-time after unroll

        bf16x8 A[2][2], B[2][4];
        #pragma unroll
        for (int ks = 0; ks < 2; ++ks) {
            if constexpr (USE_WS) {
                A[ks][0] = *(const bf16x8*)(wA + (size_t)step * 8192 + ks * 4096);
                A[ks][1] = *(const bf16x8*)(wA + (size_t)step * 8192 + ks * 4096 + 512);
            } else {
                #pragma unroll
                for (int j = 0; j < 8; ++j) {
                    A[ks][0][j] = (__bf16)w[(mb + l31) * 576 + (h * 32 + (2 * ks + l5) * 8 + j) * 9 + s];
                    A[ks][1][j] = (__bf16)w[(mb + 32 + l31) * 576 + (h * 32 + (2 * ks + l5) * 8 + j) * 9 + s];
                }
            }
            const int rowOff = ((waveR + kh) * 8 + h * 4 + ks * 2 + l5) * 2080;
            #pragma unroll
            for (int n = 0; n < 4; ++n)
                B[ks][n] = *(const bf16x8*)(smem + XS_OFF + rowOff + (n * 32 + l31 + kw) * 16);
        }
        #pragma unroll
        for (int ks = 0; ks < 2; ++ks)
            #pragma unroll
            for (int m = 0; m < 2; ++m)
                #pragma unroll
                for (int n = 0; n < 4; ++n)
                    acc[m][n] = __builtin_amdgcn_mfma_f32_32x32x16_bf16(
                        A[ks][m], B[ks][n], acc[m][n], 0, 0, 0);
    }

    // ---- epilogue: +bias, min over couts, cross-lane, cross-wave, tanh(tanh)
    float pm[4] = {1e30f, 1e30f, 1e30f, 1e30f};
    #pragma unroll
    for (int m = 0; m < 2; ++m) {
        #pragma unroll
        for (int r = 0; r < 16; ++r) {
            float bv = bias[mb + m * 32 + (r & 3) + 8 * (r >> 2) + 4 * l5];
            #pragma unroll
            for (int n = 0; n < 4; ++n)
                pm[n] = fminf(pm[n], acc[m][n][r] + bv);
        }
    }
    #pragma unroll
    for (int n = 0; n < 4; ++n)
        pm[n] = fminf(pm[n], __shfl_xor(pm[n], 32, 64));
    if (l5 == 0) {
        #pragma unroll
        for (int n = 0; n < 4; ++n)
            pmin[(waveR * 2 + waveM) * 128 + n * 32 + l31] = pm[n];
    }
    __syncthreads();

    {
        const int hh  = tid >> 7;            // 0..1
        const int col = tid & 127;
        if (col < WO) {
            float v = fminf(pmin[(hh * 2 + 0) * 128 + col], pmin[(hh * 2 + 1) * 128 + col]);
            v = tanhf(tanhf(v));
            out[((size_t)b * HO + R + hh) * WO + col] = v;
        }
    }
}

extern "C" void kernel_launch(void* const* d_in, const int* in_sizes, int n_in,
                              void* d_out, int out_size, void* d_ws, size_t ws_size,
                              hipStream_t stream) {
    const float* x    = (const float*)d_in[0];
    const float* w    = (const float*)d_in[1];
    const float* bias = (const float*)d_in[2];
    float* out = (float*)d_out;

    const size_t ws_needed = (size_t)18 * 4 * 128 * 16;   // 147456 B
    if (ws_size >= ws_needed) {
        unsigned short* wsb = (unsigned short*)d_ws;
        wreorder_3556<<<288, 256, 0, stream>>>(w, wsb);
        conv_min_tanh_3556<true><<<NB * 63, 256, 0, stream>>>(x, w, bias, (const unsigned char*)wsb, out);
    } else {
        conv_min_tanh_3556<false><<<NB * 63, 256, 0, stream>>>(x, w, bias, nullptr, out);
    }
}

// Round 13
// 80.813 us; speedup vs baseline: 1.2416x; 1.0058x over previous
//
#include <hip/hip_runtime.h>
#include <hip/hip_bf16.h>

#define CIN  64
#define HH   128
#define WW   128
#define COUT 128
#define HO   126
#define WO   126
#define NB   32
#define HW   (HH * WW)

typedef __bf16 bf16x8 __attribute__((ext_vector_type(8)));
typedef float f32x16 __attribute__((ext_vector_type(16)));

// ws2 granule layout: [step(18)=(s,h)][kg(4)][cout(128)] 16B granules
// granule(step,kg,cout)[j] = bf16(w[cout][ci = 32h + 8kg + j][s])
__global__ void wreorder_3556(const float* __restrict__ w, unsigned short* __restrict__ ws2) {
    int e = blockIdx.x * 256 + threadIdx.x;      // 0..73727
    if (e >= 73728) return;
    int j = e & 7, cout = (e >> 3) & 127, kg = (e >> 10) & 3, h = (e >> 12) & 1, s = e >> 13;
    __bf16 v = (__bf16)w[cout * 576 + (h * 32 + kg * 8 + j) * 9 + s];
    ws2[e] = __builtin_bit_cast(unsigned short, v);
}

// LDS: xs [row(4)][cg(8)][col(130)] 16B granules (ci-major) @0 = 66560 | pmin[4][128] @66560
#define XS_OFF  0
#define PM_OFF  66560
#define SMEM_BYTES (66560 + 4 * 128 * 4)   // 68608 -> 2 blocks/CU

__device__ __forceinline__ unsigned lds_addr(const void* p) {
    return (unsigned)(unsigned long long)(const __attribute__((address_space(3))) unsigned char*)p;
}
template<int OFF>
__device__ __forceinline__ bf16x8 ds_read128(unsigned base) {
    bf16x8 d;
    asm volatile("ds_read_b128 %0, %1 offset:%c2" : "=v"(d) : "v"(base), "i"(OFF));
    return d;
}
template<int OFF>
__device__ __forceinline__ bf16x8 glob_load128(const unsigned char* sbase, unsigned voff) {
    bf16x8 d;
    asm volatile("global_load_dwordx4 %0, %1, %2 offset:%c3"
                 : "=v"(d) : "v"(voff), "s"(sbase), "i"(OFF));
    return d;
}

#define MFMA_(a, b, c) __builtin_amdgcn_mfma_f32_32x32x16_bf16((a), (b), (c), 0, 0, 0)

// step T: s = T>>1, h = T&1; kh = s/3, kw = s%3
#define S_(T)  ((T) >> 1)
#define H_(T)  ((T) & 1)
#define KH_(T) (S_(T) / 3)
#define KW_(T) (S_(T) % 3)
#define IMMB(T, KS, N) (KH_(T) * 16640 + (H_(T) * 4 + (KS) * 2) * 2080 + ((N) * 32 + KW_(T)) * 16)

template<bool USE_WS>
__global__ __launch_bounds__(256, 2)
void conv_min_tanh_3556(const float* __restrict__ x, const float* __restrict__ w,
                        const float* __restrict__ bias,
                        const unsigned char* __restrict__ wsr_b,
                        float* __restrict__ out) {
    __shared__ __align__(16) unsigned char smem[SMEM_BYTES];
    float* pmin = (float*)(smem + PM_OFF);

    // XCD-chunked bijective swizzle (2016 = 8 * 252)
    const int bid = blockIdx.x;
    const int blk = (bid & 7) * 252 + (bid >> 3);
    const int b   = blk / 63;
    const int R   = (blk - b * 63) * 2;      // output rows R, R+1; input rows R..R+3

    const int tid  = threadIdx.x;
    const int lane = tid & 63;
    const int wid  = tid >> 6;               // 0..3
    const int l31 = lane & 31;
    const int l5  = lane >> 5;
    const int waveM = wid & 1;               // cout half
    const int waveR = wid >> 1;              // output row within pair
    const int mb = waveM * 64;

    // ---- stage x rows R..R+3 into xs[row][cg][col] granules (conflict-free)
    {
        const int cg = tid >> 5, c0 = tid & 31;
        const float* xb = x + (size_t)b * CIN * HW + (size_t)(cg * 8) * HW + (size_t)R * WW + c0;
        #pragma unroll
        for (int row = 0; row < 4; ++row) {
            #pragma unroll
            for (int i = 0; i < 4; ++i) {
                union { unsigned short us[8]; int4 i4; } p;
                #pragma unroll
                for (int j = 0; j < 8; ++j) {
                    __bf16 t = (__bf16)xb[(size_t)j * HW + (size_t)row * WW + i * 32];
                    p.us[j] = __builtin_bit_cast(unsigned short, t);
                }
                *(int4*)(smem + XS_OFF + ((row * 8 + cg) * 130 + i * 32 + c0) * 16) = p.i4;
            }
        }
        if (tid < 64) {   // zero-pad cols 128,129 for all 4 rows
            int row = tid >> 4, cgz = (tid >> 1) & 7, colz = 128 + (tid & 1);
            int4 z = {0, 0, 0, 0};
            *(int4*)(smem + XS_OFF + ((row * 8 + cgz) * 130 + colz) * 16) = z;
        }
    }
    __syncthreads();

    f32x16 acc[2][4] = {};   // [m][n] : 64 cout x 128 col

    if constexpr (USE_WS) {
        // per-lane bases
        const unsigned baseB = lds_addr(smem) + (unsigned)(waveR * 16640 + l5 * 2080 + l31 * 16);
        const unsigned voffA = (unsigned)(l5 * 2048 + (mb + l31) * 16);

        bf16x8 A3[3][2][2];   // [slot(3)][ks][m]  48 VGPR
        bf16x8 B2[2][2][4];   // [slot(2)][ks][n]  64 VGPR

        #define PRELA(T) do { const unsigned _va = voffA + (T) * 8192u, _vb = _va + 4096u;   \
            A3[(T) % 3][0][0] = glob_load128<0>(wsr_b, _va);                                  \
            A3[(T) % 3][0][1] = glob_load128<512>(wsr_b, _va);                                \
            A3[(T) % 3][1][0] = glob_load128<0>(wsr_b, _vb);                                  \
            A3[(T) % 3][1][1] = glob_load128<512>(wsr_b, _vb); } while (0)

        #define PRELB(T) do {                                                                 \
            B2[(T) & 1][0][0] = ds_read128<IMMB(T,0,0)>(baseB);                               \
            B2[(T) & 1][0][1] = ds_read128<IMMB(T,0,1)>(baseB);                               \
            B2[(T) & 1][0][2] = ds_read128<IMMB(T,0,2)>(baseB);                               \
            B2[(T) & 1][0][3] = ds_read128<IMMB(T,0,3)>(baseB);                               \
            B2[(T) & 1][1][0] = ds_read128<IMMB(T,1,0)>(baseB);                               \
            B2[(T) & 1][1][1] = ds_read128<IMMB(T,1,1)>(baseB);                               \
            B2[(T) & 1][1][2] = ds_read128<IMMB(T,1,2)>(baseB);                               \
            B2[(T) & 1][1][3] = ds_read128<IMMB(T,1,3)>(baseB); } while (0)

        #define KSTEP(T) do {                                                                 \
            if ((T) <= 15)      asm volatile("s_waitcnt lgkmcnt(8) vmcnt(8)" ::: "memory");   \
            else if ((T) == 16) asm volatile("s_waitcnt lgkmcnt(8) vmcnt(4)" ::: "memory");   \
            else                asm volatile("s_waitcnt lgkmcnt(0) vmcnt(0)" ::: "memory");   \
            __builtin_amdgcn_sched_barrier(0);                                                \
            { const int _q = (T) & 1, _p = (T) % 3;                                           \
              acc[0][0] = MFMA_(A3[_p][0][0], B2[_q][0][0], acc[0][0]);                       \
              acc[0][1] = MFMA_(A3[_p][0][0], B2[_q][0][1], acc[0][1]);                       \
              acc[0][2] = MFMA_(A3[_p][0][0], B2[_q][0][2], acc[0][2]);                       \
              acc[0][3] = MFMA_(A3[_p][0][0], B2[_q][0][3], acc[0][3]);                       \
              acc[1][0] = MFMA_(A3[_p][0][1], B2[_q][0][0], acc[1][0]);                       \
              acc[1][1] = MFMA_(A3[_p][0][1], B2[_q][0][1], acc[1][1]);                       \
              acc[1][2] = MFMA_(A3[_p][0][1], B2[_q][0][2], acc[1][2]);                       \
              acc[1][3] = MFMA_(A3[_p][0][1], B2[_q][0][3], acc[1][3]);                       \
              acc[0][0] = MFMA_(A3[_p][1][0], B2[_q][1][0], acc[0][0]);                       \
              acc[0][1] = MFMA_(A3[_p][1][0], B2[_q][1][1], acc[0][1]);                       \
              acc[0][2] = MFMA_(A3[_p][1][0], B2[_q][1][2], acc[0][2]);                       \
              acc[0][3] = MFMA_(A3[_p][1][0], B2[_q][1][3], acc[0][3]);                       \
              acc[1][0] = MFMA_(A3[_p][1][1], B2[_q][1][0], acc[1][0]);                       \
              acc[1][1] = MFMA_(A3[_p][1][1], B2[_q][1][1], acc[1][1]);                       \
              acc[1][2] = MFMA_(A3[_p][1][1], B2[_q][1][2], acc[1][2]);                       \
              acc[1][3] = MFMA_(A3[_p][1][1], B2[_q][1][3], acc[1][3]); }                     \
            __builtin_amdgcn_sched_barrier(0);                                                \
            if ((T) + 2 <= 17) { PRELB((T) + 2); }                                            \
            if ((T) + 3 <= 17) { PRELA((T) + 3); }                                            \
        } while (0)

        PRELA(0); PRELB(0); PRELA(1); PRELB(1); PRELA(2);

        KSTEP(0);  KSTEP(1);  KSTEP(2);  KSTEP(3);  KSTEP(4);  KSTEP(5);
        KSTEP(6);  KSTEP(7);  KSTEP(8);  KSTEP(9);  KSTEP(10); KSTEP(11);
        KSTEP(12); KSTEP(13); KSTEP(14); KSTEP(15); KSTEP(16); KSTEP(17);

        asm volatile("s_waitcnt lgkmcnt(0) vmcnt(0)" ::: "memory");
        __builtin_amdgcn_sched_barrier(0);
    } else {
        // fallback: plain R12 loop straight from w
        #pragma unroll
        for (int step = 0; step < 18; ++step) {
            const int s = step >> 1, h = step & 1;
            const int kh = s / 3, kw = s % 3;
            bf16x8 A[2][2], B[2][4];
            #pragma unroll
            for (int ks = 0; ks < 2; ++ks) {
                #pragma unroll
                for (int j = 0; j < 8; ++j) {
                    A[ks][0][j] = (__bf16)w[(mb + l31) * 576 + (h * 32 + (2 * ks + l5) * 8 + j) * 9 + s];
                    A[ks][1][j] = (__bf16)w[(mb + 32 + l31) * 576 + (h * 32 + (2 * ks + l5) * 8 + j) * 9 + s];
                }
                const int rowOff = ((waveR + kh) * 8 + h * 4 + ks * 2 + l5) * 2080;
                #pragma unroll
                for (int n = 0; n < 4; ++n)
                    B[ks][n] = *(const bf16x8*)(smem + XS_OFF + rowOff + (n * 32 + l31 + kw) * 16);
            }
            #pragma unroll
            for (int ks = 0; ks < 2; ++ks)
                #pragma unroll
                for (int m = 0; m < 2; ++m)
                    #pragma unroll
                    for (int n = 0; n < 4; ++n)
                        acc[m][n] = MFMA_(A[ks][m], B[ks][n], acc[m][n]);
        }
    }

    // ---- epilogue: +bias, min over couts, cross-lane, cross-wave, tanh(tanh)
    float pm[4] = {1e30f, 1e30f, 1e30f, 1e30f};
    #pragma unroll
    for (int m = 0; m < 2; ++m) {
        #pragma unroll
        for (int r = 0; r < 16; ++r) {
            float bv = bias[mb + m * 32 + (r & 3) + 8 * (r >> 2) + 4 * l5];
            #pragma unroll
            for (int n = 0; n < 4; ++n)
                pm[n] = fminf(pm[n], acc[m][n][r] + bv);
        }
    }
    #pragma unroll
    for (int n = 0; n < 4; ++n)
        pm[n] = fminf(pm[n], __shfl_xor(pm[n], 32, 64));
    if (l5 == 0) {
        #pragma unroll
        for (int n = 0; n < 4; ++n)
            pmin[(waveR * 2 + waveM) * 128 + n * 32 + l31] = pm[n];
    }
    __syncthreads();

    {
        const int hh  = tid >> 7;            // 0..1
        const int col = tid & 127;
        if (col < WO) {
            float v = fminf(pmin[(hh * 2 + 0) * 128 + col], pmin[(hh * 2 + 1) * 128 + col]);
            v = tanhf(tanhf(v));
            out[((size_t)b * HO + R + hh) * WO + col] = v;
        }
    }
}

extern "C" void kernel_launch(void* const* d_in, const int* in_sizes, int n_in,
                              void* d_out, int out_size, void* d_ws, size_t ws_size,
                              hipStream_t stream) {
    const float* x    = (const float*)d_in[0];
    const float* w    = (const float*)d_in[1];
    const float* bias = (const float*)d_in[2];
    float* out = (float*)d_out;

    const size_t ws_needed = (size_t)18 * 4 * 128 * 16;   // 147456 B
    if (ws_size >= ws_needed) {
        unsigned short* wsb = (unsigned short*)d_ws;
        wreorder_3556<<<288, 256, 0, stream>>>(w, wsb);
        conv_min_tanh_3556<true><<<NB * 63, 256, 0, stream>>>(x, w, bias, (const unsigned char*)wsb, out);
    } else {
        conv_min_tanh_3556<false><<<NB * 63, 256, 0, stream>>>(x, w, bias, nullptr, out);
    }
}